// Round 24
// baseline (44.372 us; speedup 1.0000x reference)
//
#include <hip/hip_runtime.h>
#include <hip/hip_bf16.h>

// out[b][o] = sum_{i,j,kl} a0[b,i]*a1[b,j]*D23[b,kl]*T[i][j*1089+kl][o]
// Wave = (i,j): reads T[i][j*1089..(j+1)*1089][*] as ONE SEQUENTIAL 139KB
// stream (69 steps x 2KB) + the L2-hot D23T table (also sequential).
#define HSZ 32
#define KL 1089             // 33^2
#define KLP 1104            // padded to 69*16
#define NBLK 1089           // 33 rows x 33 j-blocks, one wave each
#define NT 64               // partial output tiles
#define DEPTH 6             // ring slots (4KB: 2KB T + 2KB D23)

// ws layout (bytes): nhTg @ 0 (planes a0,a1: 2112 floats);
//                    D23T @ 16384 (1104*32 floats = 141,312 B);
//                    tiles @ 163840 (64*1024 floats)
#define OFF_D23   16384
#define OFF_TILES 163840

typedef short bf16x8 __attribute__((ext_vector_type(8)));
typedef float f32x16 __attribute__((ext_vector_type(16)));

__device__ inline short f2bf(float f) {
  __hip_bfloat16 h = __float2bfloat16(f);  // RTNE; pairs into v_cvt_pk_bf16_f32
  return __builtin_bit_cast(short, h);
}

// k_pre: blk<64 zero tiles; blk 64..69 build D23T[kl*32+b] (zero pad);
//        blk 70 builds nhTg planes a0,a1 (row 32 = 1.0 bias).
__global__ __launch_bounds__(256) void k_pre(const float* __restrict__ nh,
                                             float* __restrict__ nhTg,
                                             float* __restrict__ D23T,
                                             float* __restrict__ tiles) {
  const int blk = (int)blockIdx.x;
  const int t = (int)threadIdx.x;
  if (blk < 64) {
    ((float4*)tiles)[blk * 256 + t] = make_float4(0.f, 0.f, 0.f, 0.f);
  } else if (blk < 70) {
    for (int x = (blk - 64) * 256 + t; x < KLP * 32; x += 6 * 256) {
      const int kl = x >> 5;
      const int b = x & 31;
      float v = 0.f;
      if (kl < KL) {
        const int k = kl / 33;
        const int l = kl - k * 33;
        const float a2 = (k < HSZ) ? nh[b * 128 + 64 + k] : 1.0f;
        const float a3 = (l < HSZ) ? nh[b * 128 + 96 + l] : 1.0f;
        v = a2 * a3;
      }
      D23T[x] = v;
    }
  } else {
    for (int x = t; x < 2 * 1056; x += 256) {
      const int d = x / 1056;
      const int rem = x - d * 1056;
      const int row = rem >> 5;
      const int b = rem & 31;
      nhTg[x] = (row < HSZ) ? nh[b * 128 + d * 32 + row] : 1.0f;
    }
  }
}

// Main: one wave per block = (i = blk/33, j = blk%33).
__global__ __launch_bounds__(64) void k_main(const float* __restrict__ T,
                                             const float* __restrict__ nhTg,
                                             const float* __restrict__ D23T,
                                             float* __restrict__ tiles) {
  __shared__ float lds[DEPTH * 1024];  // slot: [512 T][512 D23] floats
  const int blk = blockIdx.x;
  const int i = blk / 33;
  const int j = blk - i * 33;
  const int l = (int)threadIdx.x;  // 0..63
  const int bo = l & 31;           // A row (b) / B col (o)
  const int g = l >> 5;            // k-group: k = 8*g + e

  // Per-wave scalar weight c = a0[i][bo] * a1[j][bo] (coalesced loads),
  // drained before the DMA stream so vmcnt accounting stays pure.
  const float c = nhTg[i * 32 + bo] * nhTg[1056 + j * 32 + bo];
  asm volatile("" :: "v"(c) : "memory");

  const char* Tspan = (const char*)T + ((size_t)i * 35937 + (size_t)j * KL) * 128;
  const char* Db = (const char*)D23T;
  // step-68 T srcs (kl 1088..1103: only q=0, l<8 valid; else clamp to span start)
  const size_t s68_0 = (l < 8) ? ((size_t)68 * 2048 + l * 16) : 0;

#define ISSUE(row_, slot_)                                                    \
  {                                                                           \
    _Pragma("unroll")                                                         \
    for (int q = 0; q < 2; ++q) {                                             \
      __builtin_amdgcn_global_load_lds(                                       \
          (const __attribute__((address_space(1))) void*)(                    \
              Tspan + (size_t)(row_)*2048 + q * 1024 + l * 16),               \
          (__attribute__((address_space(3))) void*)(                          \
              &lds[(slot_)*1024 + q * 256]),                                  \
          16, 0, 0);                                                          \
    }                                                                         \
    _Pragma("unroll")                                                         \
    for (int q = 0; q < 2; ++q) {                                             \
      __builtin_amdgcn_global_load_lds(                                       \
          (const __attribute__((address_space(1))) void*)(                    \
              Db + (size_t)(row_)*2048 + q * 1024 + l * 16),                  \
          (__attribute__((address_space(3))) void*)(                          \
              &lds[(slot_)*1024 + 512 + q * 256]),                            \
          16, 0, 0);                                                          \
    }                                                                         \
  }
#define ISSUE68(slot_)                                                        \
  {                                                                           \
    __builtin_amdgcn_global_load_lds(                                         \
        (const __attribute__((address_space(1))) void*)(Tspan + s68_0),       \
        (__attribute__((address_space(3))) void*)(&lds[(slot_)*1024]),        \
        16, 0, 0);                                                            \
    __builtin_amdgcn_global_load_lds(                                         \
        (const __attribute__((address_space(1))) void*)(Tspan),               \
        (__attribute__((address_space(3))) void*)(&lds[(slot_)*1024 + 256]),  \
        16, 0, 0);                                                            \
    _Pragma("unroll")                                                         \
    for (int q = 0; q < 2; ++q) {                                             \
      __builtin_amdgcn_global_load_lds(                                       \
          (const __attribute__((address_space(1))) void*)(                    \
              Db + (size_t)68 * 2048 + q * 1024 + l * 16),                    \
          (__attribute__((address_space(3))) void*)(                          \
              &lds[(slot_)*1024 + 512 + q * 256]),                            \
          16, 0, 0);                                                          \
    }                                                                         \
  }

  // Fill the ring: 24 DMA ops in flight.
  ISSUE(0, 0) ISSUE(1, 1) ISSUE(2, 2) ISSUE(3, 3) ISSUE(4, 4) ISSUE(5, 5)

  f32x16 acc = {};

#define STEP(i_, vm_, doIssue_, do68_)                                        \
  {                                                                           \
    asm volatile("s_waitcnt vmcnt(" #vm_ ")" ::: "memory");                   \
    __builtin_amdgcn_sched_barrier(0);                                        \
    float tv[8], dv[8];                                                       \
    _Pragma("unroll")                                                         \
    for (int e = 0; e < 8; ++e) {                                             \
      tv[e] = lds[((i_) % DEPTH) * 1024 + (8 * g + e) * 32 + bo];             \
      dv[e] = lds[((i_) % DEPTH) * 1024 + 512 + (8 * g + e) * 32 + bo];       \
    }                                                                         \
    bf16x8 af, bfr;                                                           \
    _Pragma("unroll")                                                         \
    for (int e = 0; e < 8; ++e) {                                             \
      af[e] = f2bf(c * dv[e]);                                                \
      bfr[e] = f2bf(tv[e]);                                                   \
    }                                                                         \
    acc = __builtin_amdgcn_mfma_f32_32x32x16_bf16(af, bfr, acc, 0, 0, 0);     \
    if (doIssue_) {                                                           \
      asm volatile("s_waitcnt lgkmcnt(0)" ::: "memory");                      \
      __builtin_amdgcn_sched_barrier(0);                                      \
      if (do68_) { ISSUE68((i_) % DEPTH) }                                    \
      else { ISSUE((i_) + DEPTH, (i_) % DEPTH) }                              \
    }                                                                         \
  }

  // 69 steps (KLP/16): issue through step 62 (row 68 = clamped), then drain.
  STEP(0, 20, 1, 0)  STEP(1, 20, 1, 0)  STEP(2, 20, 1, 0)  STEP(3, 20, 1, 0)
  STEP(4, 20, 1, 0)  STEP(5, 20, 1, 0)  STEP(6, 20, 1, 0)  STEP(7, 20, 1, 0)
  STEP(8, 20, 1, 0)  STEP(9, 20, 1, 0)  STEP(10, 20, 1, 0) STEP(11, 20, 1, 0)
  STEP(12, 20, 1, 0) STEP(13, 20, 1, 0) STEP(14, 20, 1, 0) STEP(15, 20, 1, 0)
  STEP(16, 20, 1, 0) STEP(17, 20, 1, 0) STEP(18, 20, 1, 0) STEP(19, 20, 1, 0)
  STEP(20, 20, 1, 0) STEP(21, 20, 1, 0) STEP(22, 20, 1, 0) STEP(23, 20, 1, 0)
  STEP(24, 20, 1, 0) STEP(25, 20, 1, 0) STEP(26, 20, 1, 0) STEP(27, 20, 1, 0)
  STEP(28, 20, 1, 0) STEP(29, 20, 1, 0) STEP(30, 20, 1, 0) STEP(31, 20, 1, 0)
  STEP(32, 20, 1, 0) STEP(33, 20, 1, 0) STEP(34, 20, 1, 0) STEP(35, 20, 1, 0)
  STEP(36, 20, 1, 0) STEP(37, 20, 1, 0) STEP(38, 20, 1, 0) STEP(39, 20, 1, 0)
  STEP(40, 20, 1, 0) STEP(41, 20, 1, 0) STEP(42, 20, 1, 0) STEP(43, 20, 1, 0)
  STEP(44, 20, 1, 0) STEP(45, 20, 1, 0) STEP(46, 20, 1, 0) STEP(47, 20, 1, 0)
  STEP(48, 20, 1, 0) STEP(49, 20, 1, 0) STEP(50, 20, 1, 0) STEP(51, 20, 1, 0)
  STEP(52, 20, 1, 0) STEP(53, 20, 1, 0) STEP(54, 20, 1, 0) STEP(55, 20, 1, 0)
  STEP(56, 20, 1, 0) STEP(57, 20, 1, 0) STEP(58, 20, 1, 0) STEP(59, 20, 1, 0)
  STEP(60, 20, 1, 0) STEP(61, 20, 1, 0) STEP(62, 20, 1, 1)
  STEP(63, 20, 0, 0) STEP(64, 16, 0, 0) STEP(65, 12, 0, 0)
  STEP(66, 8, 0, 0)  STEP(67, 4, 0, 0)  STEP(68, 0, 0, 0)
#undef STEP
#undef ISSUE68
#undef ISSUE

  // Atomic accumulate into one of NT partial tiles (r23 epilogue).
  // C/D layout (m74/m101): col=lane&31, row=(r&3)+8*(r>>2)+4*(lane>>5)
  float* tp = tiles + (size_t)(blk & (NT - 1)) * 1024;
#pragma unroll
  for (int r = 0; r < 16; ++r) {
    const int brow = (r & 3) + 8 * (r >> 2) + 4 * g;
    atomicAdd(tp + brow * 32 + bo, acc[r]);
  }
}

// Final reduce (r23 verbatim): out[idx] = sum over NT tiles.
__global__ __launch_bounds__(256) void k_red(const float* __restrict__ tiles,
                                             float* __restrict__ out) {
  const int idx = blockIdx.x * 256 + (int)threadIdx.x;
  float s = 0.f;
  for (int t = 0; t < NT; ++t) s += tiles[(size_t)t * 1024 + idx];
  out[idx] = s;
}

extern "C" void kernel_launch(void* const* d_in, const int* in_sizes, int n_in,
                              void* d_out, int out_size, void* d_ws, size_t ws_size,
                              hipStream_t stream) {
  const float* nh = (const float*)d_in[0];  // [32,4,32]
  const float* T  = (const float*)d_in[1];  // [33,33,33,33,32]
  float* out = (float*)d_out;               // [32,32] fp32
  char* ws = (char*)d_ws;
  float* nhTg  = (float*)ws;
  float* D23T  = (float*)(ws + OFF_D23);
  float* tiles = (float*)(ws + OFF_TILES);

  k_pre<<<71, 256, 0, stream>>>(nh, nhTg, D23T, tiles);
  k_main<<<NBLK, 64, 0, stream>>>(T, nhTg, D23T, tiles);
  k_red<<<4, 256, 0, stream>>>(tiles, out);
}

// Round 25
// 41.373 us; speedup vs baseline: 1.0725x; 1.0725x over previous
//
#include <hip/hip_runtime.h>
#include <hip/hip_bf16.h>

// Problem constants
#define HSZ 32
#define HP1 33
#define M3 35937            // 33^3 (flattened j,k,l)
#define TI_STRIDE 1149984   // 33^3 * 32 floats (stride of T over i)
#define TIB ((size_t)TI_STRIDE * 4)
#define NBLK 1124           // one wave per block, 32 m's per block
#define NT 64               // partial output tiles (contention 1124/64 ~ 18)
#define DEPTH 6             // LDS ring slots (4KB each)
#define NHB 6144            // LDS float offset of staged bf16 nh table (7KB)

// ws layout (bytes): a0T @ 0 (4224 B); nhBfG @ 4352 (7168 B);
//                    tiles @ 16384 (262,144 B)
#define OFF_NHBF  4352
#define OFF_TILES 16384

typedef short bf16x8 __attribute__((ext_vector_type(8)));
typedef float f32x16 __attribute__((ext_vector_type(16)));

__device__ inline short f2bf(float f) {
  __hip_bfloat16 h = __float2bfloat16(f);  // RTNE; pairs into v_cvt_pk_bf16_f32
  return __builtin_bit_cast(short, h);
}
__device__ inline float bf2f(short s) {
  return __builtin_bit_cast(float, (unsigned)(unsigned short)s << 16);
}

// Micro-prologue: 64 blocks zero tiles; block 64 builds a0T (fp32) and the
// bf16 planes a1,a2,a3 (transposed, bias row = 1.0, zero-padded to 3584).
__global__ __launch_bounds__(256) void k_pre(const float* __restrict__ nh,
                                             float* __restrict__ a0T,
                                             short* __restrict__ nhBfG,
                                             float* __restrict__ tiles) {
  const int blk = (int)blockIdx.x;
  const int t = (int)threadIdx.x;
  if (blk < 64) {
    ((float4*)tiles)[blk * 256 + t] = make_float4(0.f, 0.f, 0.f, 0.f);
  } else {
    for (int x = t; x < 1056; x += 256) {
      const int row = x >> 5;
      const int b = x & 31;
      a0T[x] = (row < HSZ) ? nh[b * 128 + row] : 1.0f;
    }
    for (int x = t; x < 3584; x += 256) {
      float v = 0.f;
      if (x < 3168) {
        const int d = x / 1056;
        const int rem = x - d * 1056;
        const int row = rem >> 5;
        const int b = rem & 31;
        v = (row < HSZ) ? nh[b * 128 + (d + 1) * 32 + row] : 1.0f;
      }
      nhBfG[x] = f2bf(v);
    }
  }
}

// Main (r23 with LDS slimmed to 31KB -> 5 blocks/CU, single-pass residency):
// a0 in VGPRs (r16 idiom); bf16 nh table staged via 7 DMA ops; ring + step
// schedule + epilogue r23-verbatim.
__global__ __launch_bounds__(64) void k_main(const float* __restrict__ T,
                                             const float* __restrict__ a0T,
                                             const short* __restrict__ nhBfG,
                                             float* __restrict__ tiles) {
  __shared__ float lds[DEPTH * 1024 + 1792];  // 24KB ring + 7KB bf16 table
  const int blk = blockIdx.x;
  const int m0 = blk * 32;
  const int l = (int)threadIdx.x;  // 0..63
  const int bo = l & 31;           // A row (b) / B col (o)
  const int g = l >> 5;            // k-group: k = 8*g + e

  // a0 preload into registers, drained BEFORE any DMA (pure vmcnt accounting).
  float a0v[HP1];
#pragma unroll
  for (int i = 0; i < HP1; ++i) a0v[i] = a0T[i * 32 + bo];
  {
    float s = 0.f;
#pragma unroll
    for (int i = 0; i < HP1; ++i) s += a0v[i];
    asm volatile("" :: "v"(s) : "memory");
  }

  // Per-lane DMA source byte offsets: op q covers row floats [q*256+4l, +4)
  const int mrel = l >> 3;
  size_t src[4];
#pragma unroll
  for (int q = 0; q < 4; ++q) {
    const bool valid = (m0 + 8 * q + mrel) < M3;
    src[q] = valid ? ((size_t)(m0 * 32 + q * 256 + l * 4) * 4) : 0;
  }
  const char* Tb = (const char*)T;
  const char* Ng = (const char*)nhBfG;

  // (1) Stage bf16 nh table -> LDS: 7 DMA ops (oldest in the vmcnt queue).
#pragma unroll
  for (int q = 0; q < 7; ++q) {
    __builtin_amdgcn_global_load_lds(
        (const __attribute__((address_space(1))) void*)(Ng + q * 1024 + l * 16),
        (__attribute__((address_space(3))) void*)(&lds[NHB + q * 256]),
        16, 0, 0);
  }

#define ISSUE(row_, slot_)                                                    \
  {                                                                           \
    _Pragma("unroll")                                                         \
    for (int q = 0; q < 4; ++q) {                                             \
      __builtin_amdgcn_global_load_lds(                                       \
          (const __attribute__((address_space(1))) void*)(                    \
              Tb + (size_t)(row_)*TIB + src[q]),                              \
          (__attribute__((address_space(3))) void*)(                          \
              &lds[(slot_)*1024 + q * 256]),                                  \
          16, 0, 0);                                                          \
    }                                                                         \
  }

  // (2) Fill the ring: 24 DMA ops in flight behind the 7 table ops.
  ISSUE(0, 0) ISSUE(1, 1) ISSUE(2, 2) ISSUE(3, 3) ISSUE(4, 4) ISSUE(5, 5)

  // (3) Wait for the table only (ring stays in flight); build df from LDS.
  asm volatile("s_waitcnt vmcnt(24)" ::: "memory");
  __builtin_amdgcn_sched_barrier(0);

  const short* nhs = (const short*)&lds[NHB];
  float df0[8], df1[8];
#pragma unroll
  for (int e = 0; e < 8; ++e) {
#pragma unroll
    for (int half = 0; half < 2; ++half) {
      const int m = m0 + 16 * half + 8 * g + e;
      const bool valid = m < M3;
      const int mc = valid ? m : (M3 - 1);
      const int j = mc / 1089;
      const int r = mc - j * 1089;
      const int kk = r / 33;
      const int ll = r - kk * 33;
      const float a1 = bf2f(nhs[j * 32 + bo]);
      const float a2 = bf2f(nhs[1056 + kk * 32 + bo]);
      const float a3 = bf2f(nhs[2112 + ll * 32 + bo]);
      const float v = valid ? (a1 * a2 * a3) : 0.0f;
      if (half == 0) df0[e] = v; else df1[e] = v;
    }
  }

  f32x16 acc = {};

#define STEP(i_, vm_, doIssue_)                                               \
  {                                                                           \
    asm volatile("s_waitcnt vmcnt(" #vm_ ")" ::: "memory");                   \
    __builtin_amdgcn_sched_barrier(0);                                        \
    float tv0[8], tv1[8];                                                     \
    _Pragma("unroll")                                                         \
    for (int e = 0; e < 8; ++e) {                                             \
      tv0[e] = lds[((i_) % DEPTH) * 1024 + (8 * g + e) * 32 + bo];            \
      tv1[e] = lds[((i_) % DEPTH) * 1024 + 512 + (8 * g + e) * 32 + bo];      \
    }                                                                         \
    bf16x8 af0, bf0, af1, bf1;                                                \
    _Pragma("unroll")                                                         \
    for (int e = 0; e < 8; ++e) {                                             \
      af0[e] = f2bf(a0v[i_] * df0[e]);                                        \
      bf0[e] = f2bf(tv0[e]);                                                  \
      af1[e] = f2bf(a0v[i_] * df1[e]);                                        \
      bf1[e] = f2bf(tv1[e]);                                                  \
    }                                                                         \
    acc = __builtin_amdgcn_mfma_f32_32x32x16_bf16(af0, bf0, acc, 0, 0, 0);    \
    acc = __builtin_amdgcn_mfma_f32_32x32x16_bf16(af1, bf1, acc, 0, 0, 0);    \
    if (doIssue_) {                                                           \
      asm volatile("s_waitcnt lgkmcnt(0)" ::: "memory");                      \
      __builtin_amdgcn_sched_barrier(0);                                      \
      ISSUE((i_) + DEPTH, (i_) % DEPTH)                                       \
    }                                                                         \
  }

  // 33 steps: steady vmcnt(20) while issuing (i<=26), then drain (r23).
  STEP(0, 20, 1)  STEP(1, 20, 1)  STEP(2, 20, 1)  STEP(3, 20, 1)
  STEP(4, 20, 1)  STEP(5, 20, 1)  STEP(6, 20, 1)  STEP(7, 20, 1)
  STEP(8, 20, 1)  STEP(9, 20, 1)  STEP(10, 20, 1) STEP(11, 20, 1)
  STEP(12, 20, 1) STEP(13, 20, 1) STEP(14, 20, 1) STEP(15, 20, 1)
  STEP(16, 20, 1) STEP(17, 20, 1) STEP(18, 20, 1) STEP(19, 20, 1)
  STEP(20, 20, 1) STEP(21, 20, 1) STEP(22, 20, 1) STEP(23, 20, 1)
  STEP(24, 20, 1) STEP(25, 20, 1) STEP(26, 20, 1) STEP(27, 20, 0)
  STEP(28, 16, 0) STEP(29, 12, 0) STEP(30, 8, 0)  STEP(31, 4, 0)
  STEP(32, 0, 0)
#undef STEP
#undef ISSUE

  // Accumulate into one of NT partial tiles (r23 epilogue verbatim).
  // C/D layout (m74/m101): col=lane&31, row=(r&3)+8*(r>>2)+4*(lane>>5)
  float* tp = tiles + (size_t)(blk & (NT - 1)) * 1024;
#pragma unroll
  for (int r = 0; r < 16; ++r) {
    const int brow = (r & 3) + 8 * (r >> 2) + 4 * g;
    atomicAdd(tp + brow * 32 + bo, acc[r]);
  }
}

// Final reduce (r23 verbatim): out[idx] = sum over NT tiles.
__global__ __launch_bounds__(256) void k_red(const float* __restrict__ tiles,
                                             float* __restrict__ out) {
  const int idx = blockIdx.x * 256 + (int)threadIdx.x;
  float s = 0.f;
  for (int t = 0; t < NT; ++t) s += tiles[(size_t)t * 1024 + idx];
  out[idx] = s;
}

extern "C" void kernel_launch(void* const* d_in, const int* in_sizes, int n_in,
                              void* d_out, int out_size, void* d_ws, size_t ws_size,
                              hipStream_t stream) {
  const float* nh = (const float*)d_in[0];  // [32,4,32]
  const float* T  = (const float*)d_in[1];  // [33,33,33,33,32]
  float* out = (float*)d_out;               // [32,32] fp32
  char* ws = (char*)d_ws;
  float* a0T   = (float*)ws;
  short* nhBfG = (short*)(ws + OFF_NHBF);
  float* tiles = (float*)(ws + OFF_TILES);

  k_pre<<<65, 256, 0, stream>>>(nh, a0T, nhBfG, tiles);
  k_main<<<NBLK, 64, 0, stream>>>(T, a0T, nhBfG, tiles);
  k_red<<<4, 256, 0, stream>>>(tiles, out);
}

// Round 26
// 39.282 us; speedup vs baseline: 1.1296x; 1.0532x over previous
//
#include <hip/hip_runtime.h>
#include <hip/hip_bf16.h>

// Problem constants
#define HSZ 32
#define HP1 33
#define M3 35937            // 33^3 (flattened j,k,l)
#define TI_STRIDE 1149984   // 33^3 * 32 floats (stride of T over i)
#define TIB ((size_t)TI_STRIDE * 4)
#define NBLK 1124           // one wave per block, 32 m's per block
#define NT 64               // partial output tiles (contention 1124/64 ~ 18)
#define DEPTH 6             // LDS ring slots (4KB each)
#define NHT 6144            // LDS float offset of staged nhT table
#define NHTG_FLOATS 4352    // staged floats (4224 real + zero pad)

// ws layout (bytes): nhTg @ 0 (17,408 B) ; tiles @ 32768 (262,144 B)
#define OFF_TILES 32768

typedef short bf16x8 __attribute__((ext_vector_type(8)));
typedef float f32x16 __attribute__((ext_vector_type(16)));

__device__ inline short f2bf(float f) {
  __hip_bfloat16 h = __float2bfloat16(f);  // RTNE; pairs into v_cvt_pk_bf16_f32
  return __builtin_bit_cast(short, h);
}

// Micro-prologue: 64 blocks zero tiles; block 64 builds transposed table
// nhTg[d*1056 + x*32 + b] (x=32 row = 1.0 bias; floats 4224.. zero pad).
__global__ __launch_bounds__(256) void k_pre(const float* __restrict__ nh,
                                             float* __restrict__ nhTg,
                                             float* __restrict__ tiles) {
  const int blk = (int)blockIdx.x;
  const int t = (int)threadIdx.x;
  if (blk < 64) {
    ((float4*)tiles)[blk * 256 + t] = make_float4(0.f, 0.f, 0.f, 0.f);
  } else {
    for (int x = t; x < NHTG_FLOATS; x += 256) {
      float v = 0.f;
      if (x < 4224) {
        const int d = x / 1056;
        const int rem = x - d * 1056;
        const int row = rem >> 5;
        const int b = rem & 31;
        v = (row < HSZ) ? nh[b * 128 + d * 32 + row] : 1.0f;
      }
      nhTg[x] = v;
    }
  }
}

// Main: one wave per block; block owns 32 m's. 6-slot x 4KB LDS DMA ring,
// counted vmcnt(20) steady state; nhT staged to LDS via 17 DMA ops issued
// before the ring; df built in-wave (hidden under ring fill); lgkmcnt(0) +
// DMA reissue placed AFTER the MFMAs (LDS latency hides under compute).
__global__ __launch_bounds__(64) void k_main(const float* __restrict__ T,
                                             const float* __restrict__ nhTg,
                                             float* __restrict__ tiles) {
  __shared__ float lds[DEPTH * 1024 + NHTG_FLOATS];  // 24KB ring + 17KB nhT
  const int blk = blockIdx.x;
  const int m0 = blk * 32;
  const int l = (int)threadIdx.x;  // 0..63
  const int bo = l & 31;           // A row (b) / B col (o)
  const int g = l >> 5;            // k-group: k = 8*g + e

  // Per-lane DMA source byte offsets: op q covers row floats [q*256+4l, +4)
  const int mrel = l >> 3;
  size_t src[4];
#pragma unroll
  for (int q = 0; q < 4; ++q) {
    const bool valid = (m0 + 8 * q + mrel) < M3;
    src[q] = valid ? ((size_t)(m0 * 32 + q * 256 + l * 4) * 4) : 0;
  }
  const char* Tb = (const char*)T;
  const char* Ng = (const char*)nhTg;

  // (1) Stage nhT -> LDS: 17 DMA ops (oldest in the vmcnt queue).
#pragma unroll
  for (int q = 0; q < 17; ++q) {
    __builtin_amdgcn_global_load_lds(
        (const __attribute__((address_space(1))) void*)(Ng + q * 1024 + l * 16),
        (__attribute__((address_space(3))) void*)(&lds[NHT + q * 256]),
        16, 0, 0);
  }

#define ISSUE(row_, slot_)                                                    \
  {                                                                           \
    _Pragma("unroll")                                                         \
    for (int q = 0; q < 4; ++q) {                                             \
      __builtin_amdgcn_global_load_lds(                                       \
          (const __attribute__((address_space(1))) void*)(                    \
              Tb + (size_t)(row_)*TIB + src[q]),                              \
          (__attribute__((address_space(3))) void*)(                          \
              &lds[(slot_)*1024 + q * 256]),                                  \
          16, 0, 0);                                                          \
    }                                                                         \
  }

  // (2) Fill the ring: 24 DMA ops in flight behind the 17 nhT ops.
  ISSUE(0, 0) ISSUE(1, 1) ISSUE(2, 2) ISSUE(3, 3) ISSUE(4, 4) ISSUE(5, 5)

  // (3) Wait for nhT only (ring stays in flight), then build df from LDS.
  asm volatile("s_waitcnt vmcnt(24)" ::: "memory");
  __builtin_amdgcn_sched_barrier(0);

  float df0[8], df1[8];
#pragma unroll
  for (int e = 0; e < 8; ++e) {
#pragma unroll
    for (int half = 0; half < 2; ++half) {
      const int m = m0 + 16 * half + 8 * g + e;
      const bool valid = m < M3;
      const int mc = valid ? m : (M3 - 1);
      const int j = mc / 1089;
      const int r = mc - j * 1089;
      const int kk = r / 33;
      const int ll = r - kk * 33;
      const float a1 = lds[NHT + 1056 + j * 32 + bo];
      const float a2 = lds[NHT + 2112 + kk * 32 + bo];
      const float a3 = lds[NHT + 3168 + ll * 32 + bo];
      const float v = valid ? (a1 * a2 * a3) : 0.0f;
      if (half == 0) df0[e] = v; else df1[e] = v;
    }
  }

  f32x16 acc = {};

#define STEP(i_, vm_, doIssue_)                                               \
  {                                                                           \
    asm volatile("s_waitcnt vmcnt(" #vm_ ")" ::: "memory");                   \
    __builtin_amdgcn_sched_barrier(0);                                        \
    float tv0[8], tv1[8];                                                     \
    const float a0 = lds[NHT + (i_)*32 + bo];                                 \
    _Pragma("unroll")                                                         \
    for (int e = 0; e < 8; ++e) {                                             \
      tv0[e] = lds[((i_) % DEPTH) * 1024 + (8 * g + e) * 32 + bo];            \
      tv1[e] = lds[((i_) % DEPTH) * 1024 + 512 + (8 * g + e) * 32 + bo];      \
    }                                                                         \
    bf16x8 af0, bf0, af1, bf1;                                                \
    _Pragma("unroll")                                                         \
    for (int e = 0; e < 8; ++e) {                                             \
      af0[e] = f2bf(a0 * df0[e]);                                             \
      bf0[e] = f2bf(tv0[e]);                                                  \
      af1[e] = f2bf(a0 * df1[e]);                                             \
      bf1[e] = f2bf(tv1[e]);                                                  \
    }                                                                         \
    acc = __builtin_amdgcn_mfma_f32_32x32x16_bf16(af0, bf0, acc, 0, 0, 0);    \
    acc = __builtin_amdgcn_mfma_f32_32x32x16_bf16(af1, bf1, acc, 0, 0, 0);    \
    if (doIssue_) {                                                           \
      asm volatile("s_waitcnt lgkmcnt(0)" ::: "memory");                      \
      __builtin_amdgcn_sched_barrier(0);                                      \
      ISSUE((i_) + DEPTH, (i_) % DEPTH)                                       \
    }                                                                         \
  }

  // 33 steps: steady vmcnt(20) while issuing (i<=26), then drain.
  STEP(0, 20, 1)  STEP(1, 20, 1)  STEP(2, 20, 1)  STEP(3, 20, 1)
  STEP(4, 20, 1)  STEP(5, 20, 1)  STEP(6, 20, 1)  STEP(7, 20, 1)
  STEP(8, 20, 1)  STEP(9, 20, 1)  STEP(10, 20, 1) STEP(11, 20, 1)
  STEP(12, 20, 1) STEP(13, 20, 1) STEP(14, 20, 1) STEP(15, 20, 1)
  STEP(16, 20, 1) STEP(17, 20, 1) STEP(18, 20, 1) STEP(19, 20, 1)
  STEP(20, 20, 1) STEP(21, 20, 1) STEP(22, 20, 1) STEP(23, 20, 1)
  STEP(24, 20, 1) STEP(25, 20, 1) STEP(26, 20, 1) STEP(27, 20, 0)
  STEP(28, 16, 0) STEP(29, 12, 0) STEP(30, 8, 0)  STEP(31, 4, 0)
  STEP(32, 0, 0)
#undef STEP
#undef ISSUE

  // Accumulate into one of NT partial tiles.
  // C/D layout (m74/m101): col=lane&31, row=(r&3)+8*(r>>2)+4*(lane>>5)
  float* tp = tiles + (size_t)(blk & (NT - 1)) * 1024;
#pragma unroll
  for (int r = 0; r < 16; ++r) {
    const int brow = (r & 3) + 8 * (r >> 2) + 4 * g;
    atomicAdd(tp + brow * 32 + bo, acc[r]);
  }
}

// Final reduce: out[idx] = sum over NT tiles.
__global__ __launch_bounds__(256) void k_red(const float* __restrict__ tiles,
                                             float* __restrict__ out) {
  const int idx = blockIdx.x * 256 + (int)threadIdx.x;
  float s = 0.f;
  for (int t = 0; t < NT; ++t) s += tiles[(size_t)t * 1024 + idx];
  out[idx] = s;
}

extern "C" void kernel_launch(void* const* d_in, const int* in_sizes, int n_in,
                              void* d_out, int out_size, void* d_ws, size_t ws_size,
                              hipStream_t stream) {
  const float* nh = (const float*)d_in[0];  // [32,4,32]
  const float* T  = (const float*)d_in[1];  // [33,33,33,33,32]
  float* out = (float*)d_out;               // [32,32] fp32
  char* ws = (char*)d_ws;
  float* nhTg  = (float*)ws;
  float* tiles = (float*)(ws + OFF_TILES);

  k_pre<<<65, 256, 0, stream>>>(nh, nhTg, tiles);
  k_main<<<NBLK, 64, 0, stream>>>(T, nhTg, tiles);
  k_red<<<4, 256, 0, stream>>>(tiles, out);
}